// Round 15
// baseline (217.885 us; speedup 1.0000x reference)
//
#include <hip/hip_runtime.h>

typedef short bf16x8 __attribute__((ext_vector_type(8)));
typedef float f32x4 __attribute__((ext_vector_type(4)));

__device__ __forceinline__ unsigned short f2bf(float f) {
    unsigned u = __float_as_uint(f);
    u += 0x7FFFu + ((u >> 16) & 1u);      // round-to-nearest-even
    return (unsigned short)(u >> 16);
}
__device__ __forceinline__ void gload_lds16(const void* g, void* l) {
    __builtin_amdgcn_global_load_lds(
        (const __attribute__((address_space(1))) void*)g,
        (__attribute__((address_space(3))) void*)l,
        16, 0, 0);
}

// ---------------------------------------------------------------- prep (r0 proven version):
// blocks [0,16384): u -> bf16 A' with row permutation A'[p*128+b*16+ll] = u[b*2048+p*16+ll]
// blocks [16384,17408): Bt[j][k], j=(g,w): n=g*16+(w&15); Bt = (w<16 ? Br[k][n] : Bi[k][n])
// blocks [17408,18432): Dt[h][j]: (w<16 ? Cr[n][h] : -Ci[n][h])
__global__ void prep(const float* __restrict__ u,
                     const float* __restrict__ Br, const float* __restrict__ Bi,
                     const float* __restrict__ Cr, const float* __restrict__ Ci,
                     unsigned short* __restrict__ A, unsigned short* __restrict__ Bt,
                     unsigned short* __restrict__ Dt) {
    int bid = blockIdx.x;
    if (bid < 16384) {
        int i = bid * 256 + threadIdx.x;
        int ro = i >> 8, c4 = i & 255;
        int p = ro >> 7, b = (ro >> 4) & 7, ll = ro & 15;
        int ri = b * 2048 + p * 16 + ll;
        float4 v = ((const float4*)u)[(size_t)ri * 256 + c4];
        ushort4 o; o.x = f2bf(v.x); o.y = f2bf(v.y); o.z = f2bf(v.z); o.w = f2bf(v.w);
        ((ushort4*)A)[i] = o;
        return;
    }
    __shared__ unsigned short tile[32][33];
    int id = bid - 16384;
    int z  = id >> 10;
    int t  = id & 1023;
    int jt = t >> 5, kt = t & 31;
    int tx = threadIdx.x & 31, ty = threadIdx.x >> 5;
    if (z == 0) {
        for (int i2 = ty; i2 < 32; i2 += 8) {
            int k = kt * 32 + i2;
            float v = (tx < 16) ? Br[(size_t)k * 512 + jt * 16 + tx]
                                : Bi[(size_t)k * 512 + jt * 16 + (tx & 15)];
            tile[tx][i2] = f2bf(v);
        }
        __syncthreads();
        for (int i2 = ty; i2 < 32; i2 += 8)
            Bt[(size_t)(jt * 32 + i2) * 1024 + kt * 32 + tx] = tile[i2][tx];
    } else {
        for (int i2 = ty; i2 < 32; i2 += 8) {
            float v = (i2 < 16) ? Cr[(size_t)(jt * 16 + i2) * 1024 + kt * 32 + tx]
                                : -Ci[(size_t)(jt * 16 + (i2 & 15)) * 1024 + kt * 32 + tx];
            tile[i2][tx] = f2bf(v);
        }
        __syncthreads();
        for (int i2 = ty; i2 < 32; i2 += 8)
            Dt[(size_t)(kt * 32 + i2) * 1024 + jt * 32 + tx] = tile[tx][i2];
    }
}

// Shared LDS involution (r11-verified, 0 conflicts): 2 tile-rows per 128B LDS row;
// slot sg of LDS row jg holds global row 2jg+(snom>>2), quarter snom&3, snom=sg^(jg&7);
// gload_lds dest LINEAR, global SOURCE inverse-permuted (rule 21). Read slot
// sr = (((lm&1)<<2)|lq) ^ (lm>>1) inverts it -> conflict-free.
// A/B (both use MERGED cadence, r11's winner):
//   gemm1 = 4-wave 128x256, grid 512 = 2 barrier domains/CU, ring-2, vmcnt(0)
//   gemm2 = 8-wave 256x256, grid 256 = 1 domain/CU, 4-ring, counted vmcnt(8)
// Only variable between them = domain count / ring depth.

#define SBAR __builtin_amdgcn_sched_barrier(0)

// ================================================================ 4-wave variant (gemm1)
#define KSETUP4(AP, BP)                                                             \
    const int tid = threadIdx.x, wave = tid >> 6, lane = tid & 63;                  \
    const int lm = lane & 15, lq = lane >> 4;                                       \
    const int wr = wave >> 1, wc = wave & 1;                                        \
    const int id = blockIdx.x, xcd = id & 7, j = id >> 3;                           \
    const int p    = xcd * 16 + (j >> 2);                                           \
    const int row0 = p * 128;                                                       \
    const int col0 = (j & 3) * 256;                                                 \
    const int jg0 = tid >> 3, sg = tid & 7;                                         \
    const int snom = sg ^ (jg0 & 7);                                                \
    const int srow = 2 * jg0 + (snom >> 2);                                         \
    const int scol = (snom & 3) * 16;                                               \
    const char* gA0 = (const char*)(AP) + (size_t)(row0 + srow) * 2048 + scol;      \
    const char* gB0 = (const char*)(BP) + (size_t)(col0 + srow) * 2048 + scol;      \
    const int d0 = tid * 16;                                                        \
    const int sr = (((lm & 1) << 2) | lq) ^ (lm >> 1);                              \
    const int rdA = wr * 4096 + (lm >> 1) * 128 + sr * 16;                          \
    const int rdB = 8192 + wc * 8192 + (lm >> 1) * 128 + sr * 16;                   \
    f32x4 acc[4][8] = {};

#define STAGE4(t_) do {                                                             \
    char* base_ = (char*)LDS + ((t_) & 1) * 24576;                                  \
    size_t ko_ = (size_t)(t_) * 64;                                                 \
    gload_lds16(gA0 + ko_,              base_ + d0);                                \
    gload_lds16(gA0 + ko_ +  64 * 2048, base_ + 4096  + d0);                        \
    gload_lds16(gB0 + ko_,              base_ + 8192  + d0);                        \
    gload_lds16(gB0 + ko_ +  64 * 2048, base_ + 12288 + d0);                        \
    gload_lds16(gB0 + ko_ + 128 * 2048, base_ + 16384 + d0);                        \
    gload_lds16(gB0 + ko_ + 192 * 2048, base_ + 20480 + d0); } while (0)

#define KTILE4(t_, DOST) {                                                          \
    const char* pa = (char*)LDS + ((t_) & 1) * 24576 + rdA;                         \
    const char* pb = (char*)LDS + ((t_) & 1) * 24576 + rdB;                         \
    bf16x8 af[4], bfr[8];                                                           \
    _Pragma("unroll")                                                               \
    for (int mi_ = 0; mi_ < 4; ++mi_) af[mi_] = *(const bf16x8*)(pa + mi_ * 1024);  \
    _Pragma("unroll")                                                               \
    for (int ni_ = 0; ni_ < 8; ++ni_) bfr[ni_] = *(const bf16x8*)(pb + ni_ * 1024); \
    if (DOST) { STAGE4((t_) + 1); }                                                 \
    SBAR;                                                                           \
    asm volatile("s_waitcnt lgkmcnt(0)"); SBAR;                                     \
    __builtin_amdgcn_s_setprio(1);                                                  \
    _Pragma("unroll")                                                               \
    for (int mi_ = 0; mi_ < 4; ++mi_)                                               \
        _Pragma("unroll")                                                           \
        for (int ni_ = 0; ni_ < 8; ++ni_)                                           \
            acc[mi_][ni_] = __builtin_amdgcn_mfma_f32_16x16x32_bf16(                \
                af[mi_], bfr[ni_], acc[mi_][ni_], 0, 0, 0);                         \
    __builtin_amdgcn_s_setprio(0);                                                  \
    SBAR;                                                                           \
    asm volatile("s_waitcnt vmcnt(0)");                                             \
    __builtin_amdgcn_s_barrier(); SBAR;                                             \
}

#define KMAIN4()                                                                    \
    STAGE4(0); SBAR;                                                                \
    asm volatile("s_waitcnt vmcnt(0)");                                             \
    __builtin_amdgcn_s_barrier(); SBAR;                                             \
    for (int t = 0; t < 31; ++t) { KTILE4(t, 1) }                                   \
    KTILE4(31, 0)

// ================================================================ 8-wave variant (gemm2)
#define KSETUP8(AP, BP)                                                             \
    const int tid = threadIdx.x, lane = tid & 63, wave = tid >> 6;                  \
    const int lm = lane & 15, lq = lane >> 4;                                       \
    const int wr = wave >> 2, wc = wave & 3;                                        \
    const int id = blockIdx.x;                                                      \
    const int T = (id & 7) * 32 + (id >> 3);                                        \
    const int bm = T >> 2, bn = T & 3;                                              \
    const int row0 = bm * 256, col0 = bn * 256;                                     \
    const int jg = tid >> 3, sg = tid & 7;                                          \
    const int snom = sg ^ (jg & 7);                                                 \
    const int srow = 2 * jg + (snom >> 2);                                          \
    const int scol = (snom & 3) * 16;                                               \
    const char* gA = (const char*)(AP) + (size_t)(row0 + srow) * 2048 + scol;       \
    const char* gB = (const char*)(BP) + (size_t)(col0 + srow) * 2048 + scol;       \
    const int d0 = tid * 16;                                                        \
    const int sr = (((lm & 1) << 2) | lq) ^ (lm >> 1);                              \
    const char* rA = (char*)LDS + wr * 8192 + (lm >> 1) * 128 + sr * 16;            \
    const char* rB = (char*)LDS + 16384 + wc * 4096 + (lm >> 1) * 128 + sr * 16;    \
    f32x4 acc[8][4] = {};

#define STAGE_A8(t_) do { size_t o_ = (size_t)(t_) * 64;                            \
    char* b_ = (char*)LDS + ((t_) & 3) * 32768;                                     \
    gload_lds16(gA + o_, b_ + d0);                                                  \
    gload_lds16(gA + o_ + 128 * 2048, b_ + d0 + 8192); } while (0)

#define STAGE_B8(t_) do { size_t o_ = (size_t)(t_) * 64;                            \
    char* b_ = (char*)LDS + ((t_) & 3) * 32768 + 16384;                             \
    gload_lds16(gB + o_, b_ + d0);                                                  \
    gload_lds16(gB + o_ + 128 * 2048, b_ + d0 + 8192); } while (0)

#define KTILE8(t_, DOST, VMS) {                                                     \
    const char* pa = rA + ((t_) & 3) * 32768;                                       \
    const char* pb = rB + ((t_) & 3) * 32768;                                       \
    bf16x8 av[8], bv[4];                                                            \
    _Pragma("unroll")                                                               \
    for (int i_ = 0; i_ < 4; ++i_) av[i_] = *(const bf16x8*)(pa + i_ * 1024);       \
    _Pragma("unroll")                                                               \
    for (int i_ = 0; i_ < 4; ++i_) av[4 + i_] = *(const bf16x8*)(pa + 4096 + i_ * 1024); \
    _Pragma("unroll")                                                               \
    for (int i_ = 0; i_ < 4; ++i_) bv[i_] = *(const bf16x8*)(pb + i_ * 1024);       \
    if (DOST) { STAGE_A8((t_) + 3); STAGE_B8((t_) + 3); }                           \
    SBAR;                                                                           \
    asm volatile("s_waitcnt lgkmcnt(0)"); SBAR;                                     \
    __builtin_amdgcn_s_setprio(1);                                                  \
    _Pragma("unroll")                                                               \
    for (int mi_ = 0; mi_ < 8; ++mi_)                                               \
        _Pragma("unroll")                                                           \
        for (int ni_ = 0; ni_ < 4; ++ni_)                                           \
            acc[mi_][ni_] = __builtin_amdgcn_mfma_f32_16x16x32_bf16(                \
                av[mi_], bv[ni_], acc[mi_][ni_], 0, 0, 0);                          \
    __builtin_amdgcn_s_setprio(0);                                                  \
    SBAR;                                                                           \
    asm volatile("s_waitcnt vmcnt(" VMS ")");                                       \
    __builtin_amdgcn_s_barrier(); SBAR;                                             \
}

#define KMAIN8()                                                                    \
    STAGE_A8(0); STAGE_B8(0); STAGE_A8(1); STAGE_B8(1); STAGE_A8(2); STAGE_B8(2);   \
    SBAR;                                                                           \
    asm volatile("s_waitcnt vmcnt(8)");                                             \
    __builtin_amdgcn_s_barrier(); SBAR;                                             \
    for (int t = 0; t < 29; ++t) { KTILE8(t, 1, "8") }                              \
    KTILE8(29, 0, "4")                                                              \
    KTILE8(30, 0, "0")                                                              \
    KTILE8(31, 0, "0")

// ---------------------------------------------------------------- GEMM1 (4-wave, 2 domains/CU)
// r0-verbatim epilogue: wr==0 handles b=0..3 (partials -> LDS), wr==1 continues b=4..7.
__global__ __launch_bounds__(256, 2)
void gemm1_fused(const unsigned short* __restrict__ A, const unsigned short* __restrict__ Bt,
                 const int* __restrict__ len, const float* __restrict__ nu_log,
                 const float* __restrict__ th_log, unsigned short* __restrict__ X) {
    __shared__ __attribute__((aligned(16))) char LDS[49152];   // ring-2 x 24 KB
    KSETUP4(A, Bt)
    KMAIN4()

    __syncthreads();                        // K-loop LDS reads complete; LDS reusable
    float* tot = (float*)LDS;               // [wc][32][64 lanes] fp32, 16 KB
    const float inv2pi = 0.15915494309189535f;
    const float twopi  = 6.283185307179586f;

    int lenv[8];
#pragma unroll
    for (int b = 0; b < 8; ++b) lenv[b] = len[b];
    float nuv[4], rvv[4];
#pragma unroll
    for (int g = 0; g < 4; ++g) {
        int n = (col0 >> 1) + wc * 64 + g * 16 + lm;
        nuv[g] = __expf(nu_log[n]);
        rvv[g] = __expf(th_log[n]) * inv2pi;
    }
    const int l_lo = p * 16 + lq * 4;

    if (wr == 0) {
#pragma unroll
        for (int g = 0; g < 4; ++g) {
#pragma unroll
            for (int r = 0; r < 4; ++r) {
                float sr_ = 0.f, si_ = 0.f;
                int l = l_lo + r;
                float lp1 = (float)(l + 1);
#pragma unroll
                for (int mi = 0; mi < 4; ++mi) {
                    int b = mi;                           // wr==0: b = 0..3
                    float e = fmaxf((float)lenv[b] - lp1, 0.f);
                    float mag = __expf(-e * nuv[g]);
                    float ar = e * rvv[g]; ar -= floorf(ar);
                    float sn, cs; __sincosf(ar * twopi, &sn, &cs);
                    float Lr = mag * cs, Li = mag * sn;
                    float Bur = acc[mi][2 * g][r], Bui = acc[mi][2 * g + 1][r];
                    sr_ += Lr * Bur - Li * Bui;
                    si_ += Lr * Bui + Li * Bur;
                    size_t rowoff = ((size_t)b * 2048 + l) * 1024;
                    int c = col0 + wc * 128 + g * 32 + lm;
                    X[rowoff + c]      = f2bf(sr_);
                    X[rowoff + c + 16] = f2bf(si_);
                }
                int f = (g * 4 + r) * 2;
                tot[(wc * 32 + f) * 64 + lane]     = sr_;
                tot[(wc * 32 + f + 1) * 64 + lane] = si_;
            }
        }
    }
    __syncthreads();
    if (wr == 1) {
#pragma unroll
        for (int g = 0; g < 4; ++g) {
#pragma unroll
            for (int r = 0; r < 4; ++r) {
                int f = (g * 4 + r) * 2;
                float sr_ = tot[(wc * 32 + f) * 64 + lane];
                float si_ = tot[(wc * 32 + f + 1) * 64 + lane];
                int l = l_lo + r;
                float lp1 = (float)(l + 1);
#pragma unroll
                for (int mi = 0; mi < 4; ++mi) {
                    int b = 4 + mi;                       // wr==1: b = 4..7
                    float e = fmaxf((float)lenv[b] - lp1, 0.f);
                    float mag = __expf(-e * nuv[g]);
                    float ar = e * rvv[g]; ar -= floorf(ar);
                    float sn, cs; __sincosf(ar * twopi, &sn, &cs);
                    float Lr = mag * cs, Li = mag * sn;
                    float Bur = acc[mi][2 * g][r], Bui = acc[mi][2 * g + 1][r];
                    sr_ += Lr * Bur - Li * Bui;
                    si_ += Lr * Bui + Li * Bur;
                    size_t rowoff = ((size_t)b * 2048 + l) * 1024;
                    int c = col0 + wc * 128 + g * 32 + lm;
                    X[rowoff + c]      = f2bf(sr_);
                    X[rowoff + c + 16] = f2bf(si_);
                }
            }
        }
    }
}

// ---------------------------------------------------------------- GEMM2 (8-wave merged, r11 winner)
__global__ __launch_bounds__(512, 2)
void gemm2(const unsigned short* __restrict__ X, const unsigned short* __restrict__ Dt,
           float* __restrict__ Y) {
    __shared__ __attribute__((aligned(16))) char LDS[131072];   // 4-ring x 32 KB
    KSETUP8(X, Dt)
    KMAIN8()

#pragma unroll
    for (int mi = 0; mi < 8; ++mi) {
#pragma unroll
        for (int ni = 0; ni < 4; ++ni) {
            int c  = col0 + wc * 64 + ni * 16 + lm;
            int r0 = row0 + wr * 128 + mi * 16 + lq * 4;
#pragma unroll
            for (int r = 0; r < 4; ++r)
                Y[(size_t)(r0 + r) * 1024 + c] = acc[mi][ni][r];
        }
    }
}

// ----------------------------------------------------------------
extern "C" void kernel_launch(void* const* d_in, const int* in_sizes, int n_in,
                              void* d_out, int out_size, void* d_ws, size_t ws_size,
                              hipStream_t stream) {
    const float* u      = (const float*)d_in[0];   // (8,2048,1024) f32
    const int*   len    = (const int*)d_in[1];     // (8,)
    const float* nu_log = (const float*)d_in[2];   // (512,)
    const float* th_log = (const float*)d_in[3];   // (512,)
    const float* Br     = (const float*)d_in[4];   // (1024,512)
    const float* Bi     = (const float*)d_in[5];   // (1024,512)
    const float* Cr     = (const float*)d_in[6];   // (512,1024)
    const float* Ci     = (const float*)d_in[7];   // (512,1024)
    float* y = (float*)d_out;                      // (8,2048,1024) f32

    char* ws = (char*)d_ws;
    unsigned short* A  = (unsigned short*)(ws);                 // 32 MB  (u bf16, rows permuted)
    unsigned short* X  = (unsigned short*)(ws + 33554432);      // 32 MB  (phase+cumsum result)
    unsigned short* Bt = (unsigned short*)(ws + 67108864);      //  2 MB
    unsigned short* Dt = (unsigned short*)(ws + 69206016);      //  2 MB

    prep<<<18432, 256, 0, stream>>>(u, Br, Bi, Cr, Ci, A, Bt, Dt);
    gemm1_fused<<<512, 256, 0, stream>>>(A, Bt, len, nu_log, th_log, X);
    gemm2<<<256, 512, 0, stream>>>(X, Dt, y);
}

// Round 17
// 213.068 us; speedup vs baseline: 1.0226x; 1.0226x over previous
//
#include <hip/hip_runtime.h>

typedef short bf16x8 __attribute__((ext_vector_type(8)));
typedef float f32x4 __attribute__((ext_vector_type(4)));

__device__ __forceinline__ unsigned short f2bf(float f) {
    unsigned u = __float_as_uint(f);
    u += 0x7FFFu + ((u >> 16) & 1u);      // round-to-nearest-even
    return (unsigned short)(u >> 16);
}
__device__ __forceinline__ void gload_lds16(const void* g, void* l) {
    __builtin_amdgcn_global_load_lds(
        (const __attribute__((address_space(1))) void*)g,
        (__attribute__((address_space(3))) void*)l,
        16, 0, 0);
}

// ---------------------------------------------------------------- prep (r0 proven version)
__global__ void prep(const float* __restrict__ u,
                     const float* __restrict__ Br, const float* __restrict__ Bi,
                     const float* __restrict__ Cr, const float* __restrict__ Ci,
                     unsigned short* __restrict__ A, unsigned short* __restrict__ Bt,
                     unsigned short* __restrict__ Dt) {
    int bid = blockIdx.x;
    if (bid < 16384) {
        int i = bid * 256 + threadIdx.x;
        int ro = i >> 8, c4 = i & 255;
        int p = ro >> 7, b = (ro >> 4) & 7, ll = ro & 15;
        int ri = b * 2048 + p * 16 + ll;
        float4 v = ((const float4*)u)[(size_t)ri * 256 + c4];
        ushort4 o; o.x = f2bf(v.x); o.y = f2bf(v.y); o.z = f2bf(v.z); o.w = f2bf(v.w);
        ((ushort4*)A)[i] = o;
        return;
    }
    __shared__ unsigned short tile[32][33];
    int id = bid - 16384;
    int z  = id >> 10;
    int t  = id & 1023;
    int jt = t >> 5, kt = t & 31;
    int tx = threadIdx.x & 31, ty = threadIdx.x >> 5;
    if (z == 0) {
        for (int i2 = ty; i2 < 32; i2 += 8) {
            int k = kt * 32 + i2;
            float v = (tx < 16) ? Br[(size_t)k * 512 + jt * 16 + tx]
                                : Bi[(size_t)k * 512 + jt * 16 + (tx & 15)];
            tile[tx][i2] = f2bf(v);
        }
        __syncthreads();
        for (int i2 = ty; i2 < 32; i2 += 8)
            Bt[(size_t)(jt * 32 + i2) * 1024 + kt * 32 + tx] = tile[i2][tx];
    } else {
        for (int i2 = ty; i2 < 32; i2 += 8) {
            float v = (i2 < 16) ? Cr[(size_t)(jt * 16 + i2) * 1024 + kt * 32 + tx]
                                : -Ci[(size_t)(jt * 16 + (i2 & 15)) * 1024 + kt * 32 + tx];
            tile[i2][tx] = f2bf(v);
        }
        __syncthreads();
        for (int i2 = ty; i2 < 32; i2 += 8)
            Dt[(size_t)(kt * 32 + i2) * 1024 + jt * 32 + tx] = tile[tx][i2];
    }
}

// Shared LDS involution (r11/r15-verified, 0 conflicts): 2 tile-rows per 128B LDS
// row; slot sg of LDS row jg holds global row 2jg+(snom>>2), quarter snom&3, with
// snom = sg^(jg&7); gload_lds dest LINEAR, global SOURCE inverse-permuted (rule 21).
// Read slot sr = (((lm&1)<<2)|lq) ^ (lm>>1) inverts it -> conflict-free.
// A/B (both 256^2 tile, MERGED cadence — the thrice-measured winner):
//   gemm1 = 8-wave (r11 winner, verbatim): 8 waves/CU, acc[8][4], vmcnt(8)
//   gemm2 = 16-wave occupancy probe: 1024 thr, acc[4][4] (~120 regs), 16 waves/CU,
//           vmcnt(4). Only variable = waves/CU (register footprint).

#define SBAR __builtin_amdgcn_sched_barrier(0)

// ================================================================ 8-wave (gemm1, r11 winner)
#define KSETUP8(AP, BP)                                                             \
    const int tid = threadIdx.x, lane = tid & 63, wave = tid >> 6;                  \
    const int lm = lane & 15, lq = lane >> 4;                                       \
    const int wr = wave >> 2, wc = wave & 3;                                        \
    const int id = blockIdx.x;                                                      \
    const int T = (id & 7) * 32 + (id >> 3);                                        \
    const int bm = T >> 2, bn = T & 3;                                              \
    const int row0 = bm * 256, col0 = bn * 256;                                     \
    const int jg = tid >> 3, sg = tid & 7;                                          \
    const int snom = sg ^ (jg & 7);                                                 \
    const int srow = 2 * jg + (snom >> 2);                                          \
    const int scol = (snom & 3) * 16;                                               \
    const char* gA = (const char*)(AP) + (size_t)(row0 + srow) * 2048 + scol;       \
    const char* gB = (const char*)(BP) + (size_t)(col0 + srow) * 2048 + scol;       \
    const int d0 = tid * 16;                                                        \
    const int sr = (((lm & 1) << 2) | lq) ^ (lm >> 1);                              \
    const char* rA = (char*)LDS + wr * 8192 + (lm >> 1) * 128 + sr * 16;            \
    const char* rB = (char*)LDS + 16384 + wc * 4096 + (lm >> 1) * 128 + sr * 16;    \
    f32x4 acc[8][4] = {};

#define STAGE_A8(t_) do { size_t o_ = (size_t)(t_) * 64;                            \
    char* b_ = (char*)LDS + ((t_) & 3) * 32768;                                     \
    gload_lds16(gA + o_, b_ + d0);                                                  \
    gload_lds16(gA + o_ + 128 * 2048, b_ + d0 + 8192); } while (0)

#define STAGE_B8(t_) do { size_t o_ = (size_t)(t_) * 64;                            \
    char* b_ = (char*)LDS + ((t_) & 3) * 32768 + 16384;                             \
    gload_lds16(gB + o_, b_ + d0);                                                  \
    gload_lds16(gB + o_ + 128 * 2048, b_ + d0 + 8192); } while (0)

#define KTILE8(t_, DOST, VMS) {                                                     \
    const char* pa = rA + ((t_) & 3) * 32768;                                       \
    const char* pb = rB + ((t_) & 3) * 32768;                                       \
    bf16x8 av[8], bv[4];                                                            \
    _Pragma("unroll")                                                               \
    for (int i_ = 0; i_ < 4; ++i_) av[i_] = *(const bf16x8*)(pa + i_ * 1024);       \
    _Pragma("unroll")                                                               \
    for (int i_ = 0; i_ < 4; ++i_) av[4 + i_] = *(const bf16x8*)(pa + 4096 + i_ * 1024); \
    _Pragma("unroll")                                                               \
    for (int i_ = 0; i_ < 4; ++i_) bv[i_] = *(const bf16x8*)(pb + i_ * 1024);       \
    if (DOST) { STAGE_A8((t_) + 3); STAGE_B8((t_) + 3); }                           \
    SBAR;                                                                           \
    asm volatile("s_waitcnt lgkmcnt(0)"); SBAR;                                     \
    __builtin_amdgcn_s_setprio(1);                                                  \
    _Pragma("unroll")                                                               \
    for (int mi_ = 0; mi_ < 8; ++mi_)                                               \
        _Pragma("unroll")                                                           \
        for (int ni_ = 0; ni_ < 4; ++ni_)                                           \
            acc[mi_][ni_] = __builtin_amdgcn_mfma_f32_16x16x32_bf16(                \
                av[mi_], bv[ni_], acc[mi_][ni_], 0, 0, 0);                          \
    __builtin_amdgcn_s_setprio(0);                                                  \
    SBAR;                                                                           \
    asm volatile("s_waitcnt vmcnt(" VMS ")");                                       \
    __builtin_amdgcn_s_barrier(); SBAR;                                             \
}

#define KMAIN8()                                                                    \
    STAGE_A8(0); STAGE_B8(0); STAGE_A8(1); STAGE_B8(1); STAGE_A8(2); STAGE_B8(2);   \
    SBAR;                                                                           \
    asm volatile("s_waitcnt vmcnt(8)");                                             \
    __builtin_amdgcn_s_barrier(); SBAR;                                             \
    for (int t = 0; t < 29; ++t) { KTILE8(t, 1, "8") }                              \
    KTILE8(29, 0, "4")                                                              \
    KTILE8(30, 0, "0")                                                              \
    KTILE8(31, 0, "0")

// ================================================================ 16-wave (gemm2 probe)
#define KSETUP16(AP, BP)                                                            \
    const int tid = threadIdx.x, lane = tid & 63, wave = tid >> 6;                  \
    const int lm = lane & 15, lq = lane >> 4;                                       \
    const int wr = wave >> 2, wc = wave & 3;                                        \
    const int id = blockIdx.x;                                                      \
    const int T = (id & 7) * 32 + (id >> 3);                                        \
    const int bm = T >> 2, bn = T & 3;                                              \
    const int row0 = bm * 256, col0 = bn * 256;                                     \
    const int jg = tid >> 3, sg = tid & 7;                                          \
    const int snom = sg ^ (jg & 7);                                                 \
    const int srow = 2 * jg + (snom >> 2);                                          \
    const int scol = (snom & 3) * 16;                                               \
    const char* gA = (const char*)(AP) + (size_t)(row0 + srow) * 2048 + scol;       \
    const char* gB = (const char*)(BP) + (size_t)(col0 + srow) * 2048 + scol;       \
    const int d0 = tid * 16;                                                        \
    const int sr = (((lm & 1) << 2) | lq) ^ (lm >> 1);                              \
    const char* rA = (char*)LDS + wr * 4096 + (lm >> 1) * 128 + sr * 16;            \
    const char* rB = (char*)LDS + 16384 + wc * 4096 + (lm >> 1) * 128 + sr * 16;    \
    f32x4 acc[4][4] = {};

#define STAGE16(t_) do { size_t o_ = (size_t)(t_) * 64;                             \
    char* b_ = (char*)LDS + ((t_) & 3) * 32768;                                     \
    gload_lds16(gA + o_, b_ + d0);                                                  \
    gload_lds16(gB + o_, b_ + 16384 + d0); } while (0)

#define KTILE16(t_, DOST, VMS) {                                                    \
    const char* pa = rA + ((t_) & 3) * 32768;                                       \
    const char* pb = rB + ((t_) & 3) * 32768;                                       \
    bf16x8 av[4], bv[4];                                                            \
    _Pragma("unroll")                                                               \
    for (int i_ = 0; i_ < 4; ++i_) av[i_] = *(const bf16x8*)(pa + i_ * 1024);       \
    _Pragma("unroll")                                                               \
    for (int i_ = 0; i_ < 4; ++i_) bv[i_] = *(const bf16x8*)(pb + i_ * 1024);       \
    if (DOST) { STAGE16((t_) + 3); }                                                \
    SBAR;                                                                           \
    asm volatile("s_waitcnt lgkmcnt(0)"); SBAR;                                     \
    __builtin_amdgcn_s_setprio(1);                                                  \
    _Pragma("unroll")                                                               \
    for (int mi_ = 0; mi_ < 4; ++mi_)                                               \
        _Pragma("unroll")                                                           \
        for (int ni_ = 0; ni_ < 4; ++ni_)                                           \
            acc[mi_][ni_] = __builtin_amdgcn_mfma_f32_16x16x32_bf16(                \
                av[mi_], bv[ni_], acc[mi_][ni_], 0, 0, 0);                          \
    __builtin_amdgcn_s_setprio(0);                                                  \
    SBAR;                                                                           \
    asm volatile("s_waitcnt vmcnt(" VMS ")");                                       \
    __builtin_amdgcn_s_barrier(); SBAR;                                             \
}

#define KMAIN16()                                                                   \
    STAGE16(0); STAGE16(1); STAGE16(2);                                             \
    SBAR;                                                                           \
    asm volatile("s_waitcnt vmcnt(4)");                                             \
    __builtin_amdgcn_s_barrier(); SBAR;                                             \
    for (int t = 0; t < 29; ++t) { KTILE16(t, 1, "4") }                             \
    KTILE16(29, 0, "2")                                                             \
    KTILE16(30, 0, "0")                                                             \
    KTILE16(31, 0, "0")

// ---------------------------------------------------------------- GEMM1 (8-wave merged, r11 winner)
// Wave wr owns l-panel pnl = 2*bm + wr (16 l's x all 8 batches, b == acc m-block):
// phase multiply + cumsum over b fully in-register.
__global__ __launch_bounds__(512, 2)
void gemm1_fused(const unsigned short* __restrict__ A, const unsigned short* __restrict__ Bt,
                 const int* __restrict__ len, const float* __restrict__ nu_log,
                 const float* __restrict__ th_log, unsigned short* __restrict__ X) {
    __shared__ __attribute__((aligned(16))) char LDS[131072];   // 4-ring x 32 KB
    KSETUP8(A, Bt)
    KMAIN8()

    const float inv2pi = 0.15915494309189535f;
    const float twopi  = 6.283185307179586f;
    int lenv[8];
#pragma unroll
    for (int b = 0; b < 8; ++b) lenv[b] = len[b];
    const int pnl  = 2 * bm + wr;
    const int l_lo = pnl * 16 + lq * 4;
#pragma unroll
    for (int gg = 0; gg < 2; ++gg) {
        const int cbase = col0 + wc * 64 + gg * 32;    // real at +lm, imag at +16+lm
        const int n = (cbase >> 5) * 16 + lm;
        const float nu = __expf(nu_log[n]);
        const float rv = __expf(th_log[n]) * inv2pi;
#pragma unroll
        for (int r = 0; r < 4; ++r) {
            const int l = l_lo + r;
            const float lp1 = (float)(l + 1);
            float sr_ = 0.f, si_ = 0.f;
#pragma unroll
            for (int b = 0; b < 8; ++b) {              // in-register cumsum over b
                float e = fmaxf((float)lenv[b] - lp1, 0.f);
                float mag = __expf(-e * nu);
                float ar = e * rv; ar -= floorf(ar);
                float sn, cs; __sincosf(ar * twopi, &sn, &cs);
                float Lr = mag * cs, Li = mag * sn;
                float Bur = acc[b][2 * gg][r], Bui = acc[b][2 * gg + 1][r];
                sr_ += Lr * Bur - Li * Bui;
                si_ += Lr * Bui + Li * Bur;
                size_t ro = ((size_t)b * 2048 + l) * 1024;
                X[ro + cbase + lm]      = f2bf(sr_);
                X[ro + cbase + lm + 16] = f2bf(si_);
            }
        }
    }
}

// ---------------------------------------------------------------- GEMM2 (16-wave occupancy probe)
__global__ __launch_bounds__(1024, 4)
void gemm2(const unsigned short* __restrict__ X, const unsigned short* __restrict__ Dt,
           float* __restrict__ Y) {
    __shared__ __attribute__((aligned(16))) char LDS[131072];   // 4-ring x 32 KB
    KSETUP16(X, Dt)
    KMAIN16()

#pragma unroll
    for (int mi = 0; mi < 4; ++mi) {
#pragma unroll
        for (int ni = 0; ni < 4; ++ni) {
            int c  = col0 + wc * 64 + ni * 16 + lm;
            int r0 = row0 + wr * 64 + mi * 16 + lq * 4;
#pragma unroll
            for (int r = 0; r < 4; ++r)
                Y[(size_t)(r0 + r) * 1024 + c] = acc[mi][ni][r];
        }
    }
}

// ----------------------------------------------------------------
extern "C" void kernel_launch(void* const* d_in, const int* in_sizes, int n_in,
                              void* d_out, int out_size, void* d_ws, size_t ws_size,
                              hipStream_t stream) {
    const float* u      = (const float*)d_in[0];   // (8,2048,1024) f32
    const int*   len    = (const int*)d_in[1];     // (8,)
    const float* nu_log = (const float*)d_in[2];   // (512,)
    const float* th_log = (const float*)d_in[3];   // (512,)
    const float* Br     = (const float*)d_in[4];   // (1024,512)
    const float* Bi     = (const float*)d_in[5];   // (1024,512)
    const float* Cr     = (const float*)d_in[6];   // (512,1024)
    const float* Ci     = (const float*)d_in[7];   // (512,1024)
    float* y = (float*)d_out;                      // (8,2048,1024) f32

    char* ws = (char*)d_ws;
    unsigned short* A  = (unsigned short*)(ws);                 // 32 MB  (u bf16, rows permuted)
    unsigned short* X  = (unsigned short*)(ws + 33554432);      // 32 MB  (phase+cumsum result)
    unsigned short* Bt = (unsigned short*)(ws + 67108864);      //  2 MB
    unsigned short* Dt = (unsigned short*)(ws + 69206016);      //  2 MB

    prep<<<18432, 256, 0, stream>>>(u, Br, Bi, Cr, Ci, A, Bt, Dt);
    gemm1_fused<<<256, 512, 0, stream>>>(A, Bt, len, nu_log, th_log, X);
    gemm2<<<256, 1024, 0, stream>>>(X, Dt, y);
}